// Round 6
// baseline (485.780 us; speedup 1.0000x reference)
//
#include <hip/hip_runtime.h>
#include <hip/hip_bf16.h>
#include <hip/hip_fp16.h>

#define LEAK 0.2f

typedef _Float16 half8  __attribute__((ext_vector_type(8)));
typedef _Float16 half4v __attribute__((ext_vector_type(4)));
typedef float    float4v __attribute__((ext_vector_type(4)));

// ================= bucketed CSR build =================
// bucket b = dst >> 7 (128 nodes/bucket). NBK <= 512. packed: src | (dloc<<17)

__global__ __launch_bounds__(256) void k_bincount(const int* __restrict__ edst,
                                                  int* __restrict__ gbkt,
                                                  int E, int ETOT, int NBK) {
    __shared__ int lh[512];
    int t = threadIdx.x;
    for (int b = t; b < NBK; b += 256) lh[b] = 0;
    __syncthreads();
    int base = blockIdx.x * 4096;
    #pragma unroll
    for (int u = 0; u < 16; ++u) {
        int e = base + u * 256 + t;
        if (e < ETOT) {
            int d = (e < E) ? edst[e] : (e - E);
            atomicAdd(&lh[d >> 7], 1);
        }
    }
    __syncthreads();
    for (int b = t; b < NBK; b += 256)
        if (lh[b]) atomicAdd(&gbkt[b], lh[b]);
}

__global__ __launch_bounds__(512) void k_bktscan(const int* __restrict__ gbkt,
                                                 int* __restrict__ bko,
                                                 int* __restrict__ gcur, int NBK) {
    int t = threadIdx.x;
    int v = (t < NBK) ? gbkt[t] : 0;
    int lane = t & 63, wid = t >> 6;
    int x = v;
    #pragma unroll
    for (int o = 1; o < 64; o <<= 1) {
        int y = __shfl_up(x, o);
        if (lane >= o) x += y;
    }
    __shared__ int ws[8];
    if (lane == 63) ws[wid] = x;
    __syncthreads();
    if (wid == 0) {
        int s = (lane < 8) ? ws[lane] : 0;
        #pragma unroll
        for (int o = 1; o < 8; o <<= 1) {
            int y = __shfl_up(s, o);
            if (lane >= o) s += y;
        }
        if (lane < 8) ws[lane] = s;
    }
    __syncthreads();
    int excl = x - v + (wid > 0 ? ws[wid - 1] : 0);
    if (t < NBK) { bko[t] = excl; gcur[t] = excl; }
    if (t == 511) bko[NBK] = excl;
}

__global__ __launch_bounds__(256) void k_binscatter(const int* __restrict__ esrc,
                                                    const int* __restrict__ edst,
                                                    int* __restrict__ gcur,
                                                    unsigned int* __restrict__ binned,
                                                    int E, int ETOT, int NBK) {
    __shared__ int lh[512];
    __shared__ int lbase[512];
    int t = threadIdx.x;
    for (int b = t; b < NBK; b += 256) lh[b] = 0;
    __syncthreads();
    int base = blockIdx.x * 4096;
    unsigned int word[16]; int bb[16], rk[16];
    #pragma unroll
    for (int u = 0; u < 16; ++u) {
        int e = base + u * 256 + t;
        bb[u] = -1;
        if (e < ETOT) {
            int s, d;
            if (e < E) { s = esrc[e]; d = edst[e]; } else { s = d = e - E; }
            int b = d >> 7;
            bb[u] = b;
            rk[u] = atomicAdd(&lh[b], 1);
            word[u] = (unsigned int)s | ((unsigned int)(d & 127) << 17);
        }
    }
    __syncthreads();
    for (int b = t; b < NBK; b += 256) {
        int c = lh[b];
        lbase[b] = c ? atomicAdd(&gcur[b], c) : 0;
    }
    __syncthreads();
    #pragma unroll
    for (int u = 0; u < 16; ++u)
        if (bb[u] >= 0) binned[lbase[bb[u]] + rk[u]] = word[u];
}

// fused: per-bucket degree count + LDS scan -> off[] + scatter into csr
__global__ __launch_bounds__(256) void k_scatter2(const unsigned int* __restrict__ binned,
                                                  const int* __restrict__ bko,
                                                  int* __restrict__ off,
                                                  int* __restrict__ csr, int N, int NBK) {
    __shared__ int deg[128];
    __shared__ int lcur[128];
    __shared__ int wt[2];
    int b = blockIdx.x, t = threadIdx.x;
    int n0 = b << 7;
    if (t < 128) deg[t] = 0;
    __syncthreads();
    int beg = bko[b], end = bko[b + 1];
    for (int i = beg + t; i < end; i += 256)
        atomicAdd(&deg[binned[i] >> 17], 1);
    __syncthreads();
    int v = 0, x = 0;
    if (t < 128) {
        v = deg[t];
        x = v;
        int lane = t & 63;
        #pragma unroll
        for (int o = 1; o < 64; o <<= 1) {
            int y = __shfl_up(x, o);
            if (lane >= o) x += y;
        }
        if (lane == 63) wt[t >> 6] = x;
    }
    __syncthreads();
    if (t < 128) {
        int excl = x - v + ((t >= 64) ? wt[0] : 0) + beg;
        lcur[t] = excl;
        int node = n0 + t;
        if (node < N) off[node] = excl;
    }
    if (b == NBK - 1 && t == 0) off[N] = end;
    __syncthreads();
    for (int i = beg + t; i < end; i += 256) {
        unsigned int u = binned[i];
        int pos = atomicAdd(&lcur[u >> 17], 1);
        csr[pos] = (int)(u & 0x1FFFF);
    }
}

// ================= W -> fp16 =================

__global__ __launch_bounds__(256) void k_wconv(const float* __restrict__ W0,
                                               const float* __restrict__ W1,
                                               const float* __restrict__ W2,
                                               _Float16* __restrict__ w16) {
    int i = blockIdx.x * 256 + threadIdx.x;
    if (i >= 3 * 16384) return;
    const float* src = (i < 16384) ? W0 : (i < 32768 ? W1 : W2);
    w16[i] = (_Float16)src[i & 16383];
}

// ================= MFMA fp16 GEMM + fused attention logits =================
// h stored channel-SLICED: Hs[slice][N][32], slice = col>>5 (4 slices of 32 ch).
// 16x16x32_f16 lane maps (m89-verified).

__global__ __launch_bounds__(256) void k_gemm_mfma(const float* __restrict__ X,
                                                   const _Float16* __restrict__ Wh,
                                                   const float* __restrict__ a_src,
                                                   const float* __restrict__ a_dst,
                                                   _Float16* __restrict__ Hs,
                                                   float* __restrict__ alsrc,
                                                   float* __restrict__ aldst, int N) {
    __shared__ _Float16 As[64][136];
    __shared__ float sS[64][2];
    __shared__ float sD[64][2];
    const int t = threadIdx.x;
    const int lane = t & 63, w = t >> 6;
    const int block_row = blockIdx.x * 64;

    if (t < 128) { sS[t >> 1][t & 1] = 0.f; sD[t >> 1][t & 1] = 0.f; }

    #pragma unroll
    for (int it = 0; it < 8; ++it) {
        int i = t + 256 * it;
        int row = i >> 5, c4 = i & 31;
        int gr = block_row + row;
        float4 xv = make_float4(0.f, 0.f, 0.f, 0.f);
        if (gr < N) xv = *(const float4*)(X + (size_t)gr * 128 + c4 * 4);
        half4v hv;
        hv[0] = (_Float16)xv.x; hv[1] = (_Float16)xv.y;
        hv[2] = (_Float16)xv.z; hv[3] = (_Float16)xv.w;
        *(half4v*)(&As[row][c4 * 4]) = hv;
    }

    const int l15 = lane & 15, kq = (lane >> 4) * 8;
    half8 bf[2][4];
    #pragma unroll
    for (int ntl = 0; ntl < 2; ++ntl) {
        int n0 = (w * 2 + ntl) * 16 + l15;
        #pragma unroll
        for (int kt = 0; kt < 4; ++kt)
            #pragma unroll
            for (int j = 0; j < 8; ++j)
                bf[ntl][kt][j] = Wh[(kt * 32 + kq + j) * 128 + n0];
    }
    __syncthreads();

    float4v acc[4][2];
    #pragma unroll
    for (int mt = 0; mt < 4; ++mt)
        #pragma unroll
        for (int ntl = 0; ntl < 2; ++ntl)
            acc[mt][ntl] = (float4v){0.f, 0.f, 0.f, 0.f};

    #pragma unroll
    for (int kt = 0; kt < 4; ++kt) {
        half8 a[4];
        #pragma unroll
        for (int mt = 0; mt < 4; ++mt)
            a[mt] = *(const half8*)(&As[mt * 16 + l15][kt * 32 + kq]);
        #pragma unroll
        for (int mt = 0; mt < 4; ++mt)
            #pragma unroll
            for (int ntl = 0; ntl < 2; ++ntl)
                acc[mt][ntl] = __builtin_amdgcn_mfma_f32_16x16x32_f16(
                    a[mt], bf[ntl][kt], acc[mt][ntl], 0, 0, 0);
    }

    // write h sliced: col tile (16 wide) sits inside one 32-ch slice
    #pragma unroll
    for (int mt = 0; mt < 4; ++mt) {
        int r0 = block_row + mt * 16 + (lane >> 4) * 4;
        #pragma unroll
        for (int ntl = 0; ntl < 2; ++ntl) {
            int col = (w * 2 + ntl) * 16 + l15;
            int slice = col >> 5, cc = col & 31;
            _Float16* dstp = Hs + ((size_t)slice * N) * 32 + cc;
            #pragma unroll
            for (int reg = 0; reg < 4; ++reg) {
                int r = r0 + reg;
                if (r < N) dstp[(size_t)r * 32] = (_Float16)acc[mt][ntl][reg];
            }
        }
    }

    // fused attention logits
    {
        int c0 = w * 32 + l15, c1 = c0 + 16;
        float as0 = a_src[c0], as1 = a_src[c1];
        float ad0 = a_dst[c0], ad1 = a_dst[c1];
        int head = w >> 1;
        #pragma unroll
        for (int mt = 0; mt < 4; ++mt) {
            #pragma unroll
            for (int reg = 0; reg < 4; ++reg) {
                float ps = (float)acc[mt][0][reg] * as0 + (float)acc[mt][1][reg] * as1;
                float pd = (float)acc[mt][0][reg] * ad0 + (float)acc[mt][1][reg] * ad1;
                #pragma unroll
                for (int o = 1; o < 16; o <<= 1) {
                    ps += __shfl_xor(ps, o);
                    pd += __shfl_xor(pd, o);
                }
                if (l15 == 0) {
                    int row = mt * 16 + (lane >> 4) * 4 + reg;
                    atomicAdd(&sS[row][head], ps);
                    atomicAdd(&sD[row][head], pd);
                }
            }
        }
    }
    __syncthreads();
    if (t < 128) {
        int row = t >> 1, head = t & 1;
        int gr = block_row + row;
        if (gr < N) {
            alsrc[gr * 2 + head] = sS[row][head];
            aldst[gr * 2 + head] = sD[row][head];
        }
    }
}

// ================= pass A: per-edge normalized softmax weights =================
// one wave64 per dst node; writes ewk[i] = (src, half2(alpha0, alpha1)) in csr order

__global__ __launch_bounds__(256) void k_alphaw(const float* __restrict__ alsrc,
                                                const float* __restrict__ aldst,
                                                const int* __restrict__ off,
                                                const int* __restrict__ csr,
                                                int2* __restrict__ ewk, int N) {
    int node = (int)((blockIdx.x * 256 + threadIdx.x) >> 6);
    int lane = threadIdx.x & 63;
    if (node >= N) return;
    int beg = off[node], end = off[node + 1];
    float ad0 = aldst[node * 2], ad1 = aldst[node * 2 + 1];

    int i0 = beg + lane;
    int s0 = 0; float w0 = 0.f, w1 = 0.f;
    if (i0 < end) {
        s0 = csr[i0];
        float2 al = *(const float2*)(&alsrc[s0 * 2]);
        float e0 = al.x + ad0; e0 = e0 > 0.f ? e0 : LEAK * e0;
        float e1 = al.y + ad1; e1 = e1 > 0.f ? e1 : LEAK * e1;
        w0 = __expf(e0); w1 = __expf(e1);
    }
    float d0 = w0, d1 = w1;
    for (int base2 = beg + 64; base2 < end; base2 += 64) {   // rare (deg > 64)
        int i = base2 + lane;
        if (i < end) {
            int s = csr[i];
            float2 al = *(const float2*)(&alsrc[s * 2]);
            float e0 = al.x + ad0; e0 = e0 > 0.f ? e0 : LEAK * e0;
            float e1 = al.y + ad1; e1 = e1 > 0.f ? e1 : LEAK * e1;
            d0 += __expf(e0); d1 += __expf(e1);
        }
    }
    #pragma unroll
    for (int o = 1; o < 64; o <<= 1) { d0 += __shfl_xor(d0, o); d1 += __shfl_xor(d1, o); }
    float inv0 = 1.f / d0, inv1 = 1.f / d1;

    if (i0 < end) {
        union { __half2 h; int i; } u;
        u.h = __halves2half2(__float2half_rn(w0 * inv0), __float2half_rn(w1 * inv1));
        ewk[i0] = make_int2(s0, u.i);
    }
    for (int base2 = beg + 64; base2 < end; base2 += 64) {
        int i = base2 + lane;
        if (i < end) {
            int s = csr[i];
            float2 al = *(const float2*)(&alsrc[s * 2]);
            float e0 = al.x + ad0; e0 = e0 > 0.f ? e0 : LEAK * e0;
            float e1 = al.y + ad1; e1 = e1 > 0.f ? e1 : LEAK * e1;
            union { __half2 h; int i; } u;
            u.h = __halves2half2(__float2half_rn(__expf(e0) * inv0),
                                 __float2half_rn(__expf(e1) * inv1));
            ewk[i] = make_int2(s, u.i);
        }
    }
}

// ================= pass B: sliced weighted gather =================
// slice = (blockIdx%8)>>1 -> XCD-pair affinity (round-robin blockIdx->XCD heuristic);
// each slice's h (N x 32ch fp16 = 3.2 MB) stays resident in that XCD's 4 MiB L2.
// wave per node; 16 edges/iter x 4 lanes/edge (16 B = 8 ch each).
// mode: 0 = bias->Out ; 1 = bias+prev->Out ; 2 = bias+prev, partial lin dot -> atomicAdd logits

__global__ __launch_bounds__(256) void k_gather(
        const _Float16* __restrict__ Hs,     // [4][N][32]
        const int2* __restrict__ ewk,
        const int* __restrict__ off,
        const float* __restrict__ bias,
        const float* __restrict__ prev,
        float* __restrict__ Out,
        const float* __restrict__ lw, const float* __restrict__ lb,
        float* __restrict__ logits, int N, int mode) {
    int b = blockIdx.x;
    int slice = (b & 7) >> 1;
    int widx = (b >> 3) * 2 + (b & 1);
    int wave0 = widx * 4 + (threadIdx.x >> 6);
    int nW = (gridDim.x >> 3) * 8;        // waves per slice
    int lane = threadIdx.x & 63;
    int p = lane & 3, q = lane >> 2;
    const _Float16* hbase = Hs + (size_t)slice * N * 32 + p * 8;
    bool head0 = slice < 2;
    int cbase = slice * 32 + p * 8;

    for (int node = wave0; node < N; node += nW) {
        int beg = off[node], end = off[node + 1];
        float acc[8];
        #pragma unroll
        for (int k = 0; k < 8; ++k) acc[k] = 0.f;

        for (int base2 = beg; base2 < end; base2 += 64) {
            int i = base2 + lane;
            int sv = 0, av = 0;
            if (i < end) { int2 e = ewk[i]; sv = e.x; av = e.y; }
            int cnt = min(64, end - base2);
            int iters = (cnt + 15) >> 4;
            for (int jj = 0; jj < iters; ++jj) {
                int sl = (jj << 4) + q;
                int sj = __shfl(sv, sl);
                int aj = __shfl(av, sl);
                __half2 ah = *(__half2*)&aj;
                float asel = head0 ? __low2float(ah) : __high2float(ah);
                const _Float16* hp = hbase + (size_t)sj * 32;
                uint4 raw = *(const uint4*)hp;    // 8 fp16
                const _Float16* h = (const _Float16*)&raw;
                #pragma unroll
                for (int k = 0; k < 8; ++k) acc[k] += asel * (float)h[k];  // v_fma_mix
            }
        }

        #pragma unroll
        for (int k = 0; k < 8; ++k) {
            acc[k] += __shfl_xor(acc[k], 4);
            acc[k] += __shfl_xor(acc[k], 8);
            acc[k] += __shfl_xor(acc[k], 16);
            acc[k] += __shfl_xor(acc[k], 32);
        }

        if (q == 0) {
            float v[8];
            #pragma unroll
            for (int k = 0; k < 8; ++k) v[k] = acc[k] + bias[cbase + k];
            if (mode >= 1) {
                float4 p0 = *(const float4*)(&prev[(size_t)node * 128 + cbase]);
                float4 p1 = *(const float4*)(&prev[(size_t)node * 128 + cbase + 4]);
                v[0] += p0.x; v[1] += p0.y; v[2] += p0.z; v[3] += p0.w;
                v[4] += p1.x; v[5] += p1.y; v[6] += p1.z; v[7] += p1.w;
            }
            #pragma unroll
            for (int k = 0; k < 8; ++k) v[k] = v[k] > 0.f ? v[k] : LEAK * v[k];
            if (mode == 2) {
                float partial = 0.f;
                #pragma unroll
                for (int k = 0; k < 8; ++k) partial += v[k] * lw[cbase + k];
                partial += __shfl_xor(partial, 1);
                partial += __shfl_xor(partial, 2);
                if (p == 0)
                    atomicAdd(&logits[node], partial + (slice == 0 ? lb[0] : 0.f));
            } else {
                *(float4*)(&Out[(size_t)node * 128 + cbase])     = make_float4(v[0], v[1], v[2], v[3]);
                *(float4*)(&Out[(size_t)node * 128 + cbase + 4]) = make_float4(v[4], v[5], v[6], v[7]);
            }
        }
    }
}

// ================= launch =================

extern "C" void kernel_launch(void* const* d_in, const int* in_sizes, int n_in,
                              void* d_out, int out_size, void* d_ws, size_t ws_size,
                              hipStream_t stream) {
    const float* x    = (const float*)d_in[0];
    const int*   edge = (const int*)d_in[1];
    const float* W[3]  = {(const float*)d_in[2], (const float*)d_in[6], (const float*)d_in[10]};
    const float* as[3] = {(const float*)d_in[3], (const float*)d_in[7], (const float*)d_in[11]};
    const float* ad[3] = {(const float*)d_in[4], (const float*)d_in[8], (const float*)d_in[12]};
    const float* bs[3] = {(const float*)d_in[5], (const float*)d_in[9], (const float*)d_in[13]};
    const float* lw = (const float*)d_in[14];
    const float* lb = (const float*)d_in[15];

    const int N    = in_sizes[0] / 128;
    const int E    = in_sizes[1] / 2;
    const int ETOT = E + N;
    const int NBK  = (N + 127) >> 7;   // requires N <= 65536 (here N = 50000)

    char* base = (char*)d_ws;
    size_t o = 0;
    auto carve = [&](size_t bytes) {
        char* p = base + o;
        o = (o + bytes + 255) & ~(size_t)255;
        return p;
    };
    int*      off    = (int*)     carve((size_t)(N + 1) * 4);
    int*      gbkt   = (int*)     carve((size_t)(NBK + 1) * 4);
    int*      bko    = (int*)     carve((size_t)(NBK + 1) * 4);
    int*      gcur   = (int*)     carve((size_t)(NBK + 1) * 4);
    unsigned* binned = (unsigned*)carve((size_t)ETOT * 4);
    int*      csr    = (int*)     carve((size_t)ETOT * 4);
    int2*     ewk    = (int2*)    carve((size_t)ETOT * 8);
    float*    alsrc  = (float*)   carve((size_t)N * 2 * 4);
    float*    aldst  = (float*)   carve((size_t)N * 2 * 4);
    _Float16* h16    = (_Float16*)carve((size_t)N * 128 * 2);
    float*    bufA   = (float*)   carve((size_t)N * 128 * 4);
    float*    bufB   = (float*)   carve((size_t)N * 128 * 4);
    _Float16* w16    = (_Float16*)carve((size_t)3 * 16384 * 2);
    (void)ws_size; (void)n_in; (void)out_size;

    const int* esrc = edge;
    const int* edst = edge + E;

    int eb = (ETOT + 4095) / 4096;

    hipMemsetAsync(gbkt, 0, (size_t)(NBK + 1) * 4, stream);
    hipMemsetAsync(d_out, 0, (size_t)N * 4, stream);   // logits accumulated atomically
    k_wconv<<<192, 256, 0, stream>>>(W[0], W[1], W[2], w16);

    // bucketed CSR build
    k_bincount<<<eb, 256, 0, stream>>>(edst, gbkt, E, ETOT, NBK);
    k_bktscan<<<1, 512, 0, stream>>>(gbkt, bko, gcur, NBK);
    k_binscatter<<<eb, 256, 0, stream>>>(esrc, edst, gcur, binned, E, ETOT, NBK);
    k_scatter2<<<NBK, 256, 0, stream>>>(binned, bko, off, csr, N, NBK);

    int gemm_blocks = (N + 63) / 64;
    int node_blocks = (N * 64 + 255) / 256;
    int gather_blocks = 8192;

    // layer 1
    k_gemm_mfma<<<gemm_blocks, 256, 0, stream>>>(x, w16, as[0], ad[0], h16, alsrc, aldst, N);
    k_alphaw<<<node_blocks, 256, 0, stream>>>(alsrc, aldst, off, csr, ewk, N);
    k_gather<<<gather_blocks, 256, 0, stream>>>(h16, ewk, off, bs[0], nullptr, bufA,
                                                lw, lb, nullptr, N, 0);
    // layer 2
    k_gemm_mfma<<<gemm_blocks, 256, 0, stream>>>(bufA, w16 + 16384, as[1], ad[1], h16, alsrc, aldst, N);
    k_alphaw<<<node_blocks, 256, 0, stream>>>(alsrc, aldst, off, csr, ewk, N);
    k_gather<<<gather_blocks, 256, 0, stream>>>(h16, ewk, off, bs[1], bufA, bufB,
                                                lw, lb, nullptr, N, 1);
    // layer 3 (+ fused final linear via per-slice atomic partial dots)
    k_gemm_mfma<<<gemm_blocks, 256, 0, stream>>>(bufB, w16 + 32768, as[2], ad[2], h16, alsrc, aldst, N);
    k_alphaw<<<node_blocks, 256, 0, stream>>>(alsrc, aldst, off, csr, ewk, N);
    k_gather<<<gather_blocks, 256, 0, stream>>>(h16, ewk, off, bs[2], bufB, nullptr,
                                                lw, lb, (float*)d_out, N, 2);
}

// Round 7
// 302.152 us; speedup vs baseline: 1.6077x; 1.6077x over previous
//
#include <hip/hip_runtime.h>
#include <hip/hip_bf16.h>
#include <hip/hip_fp16.h>

#define LEAK 0.2f

typedef _Float16 half8  __attribute__((ext_vector_type(8)));
typedef _Float16 half4v __attribute__((ext_vector_type(4)));
typedef float    float4v __attribute__((ext_vector_type(4)));

// ================= bucketed CSR build =================
// bucket b = dst >> 7 (128 nodes/bucket). NBK <= 512. packed: src | (dloc<<17)

__global__ __launch_bounds__(256) void k_bincount(const int* __restrict__ edst,
                                                  int* __restrict__ gbkt,
                                                  int E, int ETOT, int NBK) {
    __shared__ int lh[512];
    int t = threadIdx.x;
    for (int b = t; b < NBK; b += 256) lh[b] = 0;
    __syncthreads();
    int base = blockIdx.x * 4096;
    #pragma unroll
    for (int u = 0; u < 16; ++u) {
        int e = base + u * 256 + t;
        if (e < ETOT) {
            int d = (e < E) ? edst[e] : (e - E);
            atomicAdd(&lh[d >> 7], 1);
        }
    }
    __syncthreads();
    for (int b = t; b < NBK; b += 256)
        if (lh[b]) atomicAdd(&gbkt[b], lh[b]);
}

__global__ __launch_bounds__(512) void k_bktscan(const int* __restrict__ gbkt,
                                                 int* __restrict__ bko,
                                                 int* __restrict__ gcur, int NBK) {
    int t = threadIdx.x;
    int v = (t < NBK) ? gbkt[t] : 0;
    int lane = t & 63, wid = t >> 6;
    int x = v;
    #pragma unroll
    for (int o = 1; o < 64; o <<= 1) {
        int y = __shfl_up(x, o);
        if (lane >= o) x += y;
    }
    __shared__ int ws[8];
    if (lane == 63) ws[wid] = x;
    __syncthreads();
    if (wid == 0) {
        int s = (lane < 8) ? ws[lane] : 0;
        #pragma unroll
        for (int o = 1; o < 8; o <<= 1) {
            int y = __shfl_up(s, o);
            if (lane >= o) s += y;
        }
        if (lane < 8) ws[lane] = s;
    }
    __syncthreads();
    int excl = x - v + (wid > 0 ? ws[wid - 1] : 0);
    if (t < NBK) { bko[t] = excl; gcur[t] = excl; }
    if (t == 511) bko[NBK] = excl;
}

__global__ __launch_bounds__(256) void k_binscatter(const int* __restrict__ esrc,
                                                    const int* __restrict__ edst,
                                                    int* __restrict__ gcur,
                                                    unsigned int* __restrict__ binned,
                                                    int E, int ETOT, int NBK) {
    __shared__ int lh[512];
    __shared__ int lbase[512];
    int t = threadIdx.x;
    for (int b = t; b < NBK; b += 256) lh[b] = 0;
    __syncthreads();
    int base = blockIdx.x * 4096;
    unsigned int word[16]; int bb[16], rk[16];
    #pragma unroll
    for (int u = 0; u < 16; ++u) {
        int e = base + u * 256 + t;
        bb[u] = -1;
        if (e < ETOT) {
            int s, d;
            if (e < E) { s = esrc[e]; d = edst[e]; } else { s = d = e - E; }
            int b = d >> 7;
            bb[u] = b;
            rk[u] = atomicAdd(&lh[b], 1);
            word[u] = (unsigned int)s | ((unsigned int)(d & 127) << 17);
        }
    }
    __syncthreads();
    for (int b = t; b < NBK; b += 256) {
        int c = lh[b];
        lbase[b] = c ? atomicAdd(&gcur[b], c) : 0;
    }
    __syncthreads();
    #pragma unroll
    for (int u = 0; u < 16; ++u)
        if (bb[u] >= 0) binned[lbase[bb[u]] + rk[u]] = word[u];
}

// fused: per-bucket degree count + LDS scan -> off[] + scatter into csr
__global__ __launch_bounds__(256) void k_scatter2(const unsigned int* __restrict__ binned,
                                                  const int* __restrict__ bko,
                                                  int* __restrict__ off,
                                                  int* __restrict__ csr, int N, int NBK) {
    __shared__ int deg[128];
    __shared__ int lcur[128];
    __shared__ int wt[2];
    int b = blockIdx.x, t = threadIdx.x;
    int n0 = b << 7;
    if (t < 128) deg[t] = 0;
    __syncthreads();
    int beg = bko[b], end = bko[b + 1];
    for (int i = beg + t; i < end; i += 256)
        atomicAdd(&deg[binned[i] >> 17], 1);
    __syncthreads();
    int v = 0, x = 0;
    if (t < 128) {
        v = deg[t];
        x = v;
        int lane = t & 63;
        #pragma unroll
        for (int o = 1; o < 64; o <<= 1) {
            int y = __shfl_up(x, o);
            if (lane >= o) x += y;
        }
        if (lane == 63) wt[t >> 6] = x;
    }
    __syncthreads();
    if (t < 128) {
        int excl = x - v + ((t >= 64) ? wt[0] : 0) + beg;
        lcur[t] = excl;
        int node = n0 + t;
        if (node < N) off[node] = excl;
    }
    if (b == NBK - 1 && t == 0) off[N] = end;
    __syncthreads();
    for (int i = beg + t; i < end; i += 256) {
        unsigned int u = binned[i];
        int pos = atomicAdd(&lcur[u >> 17], 1);
        csr[pos] = (int)(u & 0x1FFFF);
    }
}

// ================= W -> fp16 =================

__global__ __launch_bounds__(256) void k_wconv(const float* __restrict__ W0,
                                               const float* __restrict__ W1,
                                               const float* __restrict__ W2,
                                               _Float16* __restrict__ w16) {
    int i = blockIdx.x * 256 + threadIdx.x;
    if (i >= 3 * 16384) return;
    const float* src = (i < 16384) ? W0 : (i < 32768 ? W1 : W2);
    w16[i] = (_Float16)src[i & 16383];
}

// ================= MFMA fp16 GEMM + fused attention logits =================
// h interleaved [N][128] fp16. 16x16x32_f16 lane maps (m89-verified):
//   A[m][k]: m=lane&15, k=(lane>>4)*8+j ; B[k][n]: n=lane&15, k=(lane>>4)*8+j
//   C/D[r][c]: c=lane&15, r=(lane>>4)*4+reg

__global__ __launch_bounds__(256) void k_gemm_mfma(const float* __restrict__ X,
                                                   const _Float16* __restrict__ Wh,
                                                   const float* __restrict__ a_src,
                                                   const float* __restrict__ a_dst,
                                                   _Float16* __restrict__ Hout,
                                                   float* __restrict__ alsrc,
                                                   float* __restrict__ aldst, int N) {
    __shared__ _Float16 As[64][136];   // +8 pad -> 2-way bank aliasing only (free)
    __shared__ float sS[64][2];
    __shared__ float sD[64][2];
    const int t = threadIdx.x;
    const int lane = t & 63, w = t >> 6;
    const int block_row = blockIdx.x * 64;

    if (t < 128) { sS[t >> 1][t & 1] = 0.f; sD[t >> 1][t & 1] = 0.f; }

    #pragma unroll
    for (int it = 0; it < 8; ++it) {
        int i = t + 256 * it;
        int row = i >> 5, c4 = i & 31;
        int gr = block_row + row;
        float4 xv = make_float4(0.f, 0.f, 0.f, 0.f);
        if (gr < N) xv = *(const float4*)(X + (size_t)gr * 128 + c4 * 4);
        half4v hv;
        hv[0] = (_Float16)xv.x; hv[1] = (_Float16)xv.y;
        hv[2] = (_Float16)xv.z; hv[3] = (_Float16)xv.w;
        *(half4v*)(&As[row][c4 * 4]) = hv;
    }

    const int l15 = lane & 15, kq = (lane >> 4) * 8;
    half8 bf[2][4];
    #pragma unroll
    for (int ntl = 0; ntl < 2; ++ntl) {
        int n0 = (w * 2 + ntl) * 16 + l15;
        #pragma unroll
        for (int kt = 0; kt < 4; ++kt)
            #pragma unroll
            for (int j = 0; j < 8; ++j)
                bf[ntl][kt][j] = Wh[(kt * 32 + kq + j) * 128 + n0];
    }
    __syncthreads();

    float4v acc[4][2];
    #pragma unroll
    for (int mt = 0; mt < 4; ++mt)
        #pragma unroll
        for (int ntl = 0; ntl < 2; ++ntl)
            acc[mt][ntl] = (float4v){0.f, 0.f, 0.f, 0.f};

    #pragma unroll
    for (int kt = 0; kt < 4; ++kt) {
        half8 a[4];
        #pragma unroll
        for (int mt = 0; mt < 4; ++mt)
            a[mt] = *(const half8*)(&As[mt * 16 + l15][kt * 32 + kq]);
        #pragma unroll
        for (int mt = 0; mt < 4; ++mt)
            #pragma unroll
            for (int ntl = 0; ntl < 2; ++ntl)
                acc[mt][ntl] = __builtin_amdgcn_mfma_f32_16x16x32_f16(
                    a[mt], bf[ntl][kt], acc[mt][ntl], 0, 0, 0);
    }

    #pragma unroll
    for (int mt = 0; mt < 4; ++mt) {
        int r0 = block_row + mt * 16 + (lane >> 4) * 4;
        #pragma unroll
        for (int ntl = 0; ntl < 2; ++ntl) {
            int col = (w * 2 + ntl) * 16 + l15;
            #pragma unroll
            for (int reg = 0; reg < 4; ++reg) {
                int r = r0 + reg;
                if (r < N) Hout[(size_t)r * 128 + col] = (_Float16)acc[mt][ntl][reg];
            }
        }
    }

    // fused attention logits: wave covers cols [w*32, w*32+32) -> head = w>>1
    {
        int c0 = w * 32 + l15, c1 = c0 + 16;
        float as0 = a_src[c0], as1 = a_src[c1];
        float ad0 = a_dst[c0], ad1 = a_dst[c1];
        int head = w >> 1;
        #pragma unroll
        for (int mt = 0; mt < 4; ++mt) {
            #pragma unroll
            for (int reg = 0; reg < 4; ++reg) {
                float ps = (float)acc[mt][0][reg] * as0 + (float)acc[mt][1][reg] * as1;
                float pd = (float)acc[mt][0][reg] * ad0 + (float)acc[mt][1][reg] * ad1;
                #pragma unroll
                for (int o = 1; o < 16; o <<= 1) {
                    ps += __shfl_xor(ps, o);
                    pd += __shfl_xor(pd, o);
                }
                if (l15 == 0) {
                    int row = mt * 16 + (lane >> 4) * 4 + reg;
                    atomicAdd(&sS[row][head], ps);
                    atomicAdd(&sD[row][head], pd);
                }
            }
        }
    }
    __syncthreads();
    if (t < 128) {
        int row = t >> 1, head = t & 1;
        int gr = block_row + row;
        if (gr < N) {
            alsrc[gr * 2 + head] = sS[row][head];
            aldst[gr * 2 + head] = sD[row][head];
        }
    }
}

// ================= softmax-aggregate: one wave64 per dst node, 4 edges/iter ===========
// p = lane&15 owns channels [8p, 8p+8); q = lane>>4 processes edges == q (mod 4).
// No segment-max: logits bounded, exp safe in fp32, softmax shift-invariant.
// mode: 0 = bias->Out ; 1 = bias+prev->Out ; 2 = bias+prev, fused lin dot -> logits

__global__ __launch_bounds__(256) void k_aggregate(
        const _Float16* __restrict__ H16,   // [N][128] fp16
        const float* __restrict__ alsrc,
        const float* __restrict__ aldst,
        const int* __restrict__ off, const int* __restrict__ csr,
        const float* __restrict__ bias,
        const float* __restrict__ prev,
        float* __restrict__ Out,
        const float* __restrict__ lw, const float* __restrict__ lb,
        float* __restrict__ logits, int N, int mode) {
    int node = (int)((blockIdx.x * 256 + threadIdx.x) >> 6);
    int lane = threadIdx.x & 63;
    if (node >= N) return;
    int beg = off[node], end = off[node + 1];
    float ad0 = aldst[node * 2], ad1 = aldst[node * 2 + 1];

    int p = lane & 15;
    int q = lane >> 4;
    bool head0 = p < 8;
    const _Float16* hbase = H16 + p * 8;

    float acc[8];
    #pragma unroll
    for (int i = 0; i < 8; ++i) acc[i] = 0.f;
    float dsum = 0.f;

    for (int base = beg; base < end; base += 64) {
        int i = base + lane;
        float w0 = 0.f, w1 = 0.f; int s = 0;
        if (i < end) {
            s = csr[i];
            float2 al = *(const float2*)(&alsrc[s * 2]);
            float e0 = al.x + ad0; e0 = e0 > 0.f ? e0 : LEAK * e0;
            float e1 = al.y + ad1; e1 = e1 > 0.f ? e1 : LEAK * e1;
            w0 = __expf(e0); w1 = __expf(e1);
        }
        int cnt = min(64, end - base);
        int iters = (cnt + 3) >> 2;
        int jj = 0;
        // 2x unrolled: two independent 16B gathers in flight per iteration
        for (; jj + 2 <= iters; jj += 2) {
            int sl0 = (jj << 2) + q, sl1 = sl0 + 4;
            int   sj0  = __shfl(s,  sl0);
            float w0j0 = __shfl(w0, sl0);
            float w1j0 = __shfl(w1, sl0);
            int   sj1  = __shfl(s,  sl1);
            float w0j1 = __shfl(w0, sl1);
            float w1j1 = __shfl(w1, sl1);
            float wsel0 = head0 ? w0j0 : w1j0;
            float wsel1 = head0 ? w0j1 : w1j1;
            uint4 raw0 = *(const uint4*)(hbase + (size_t)sj0 * 128);
            uint4 raw1 = *(const uint4*)(hbase + (size_t)sj1 * 128);
            const _Float16* h0 = (const _Float16*)&raw0;
            const _Float16* h1 = (const _Float16*)&raw1;
            #pragma unroll
            for (int k = 0; k < 8; ++k) acc[k] += wsel0 * (float)h0[k];
            #pragma unroll
            for (int k = 0; k < 8; ++k) acc[k] += wsel1 * (float)h1[k];
            dsum += wsel0 + wsel1;
        }
        if (jj < iters) {
            int sl = (jj << 2) + q;
            int   sj  = __shfl(s,  sl);
            float w0j = __shfl(w0, sl);
            float w1j = __shfl(w1, sl);
            float wsel = head0 ? w0j : w1j;
            uint4 raw = *(const uint4*)(hbase + (size_t)sj * 128);
            const _Float16* h = (const _Float16*)&raw;
            #pragma unroll
            for (int k = 0; k < 8; ++k) acc[k] += wsel * (float)h[k];
            dsum += wsel;
        }
    }

    #pragma unroll
    for (int i = 0; i < 8; ++i) {
        acc[i] += __shfl_xor(acc[i], 16);
        acc[i] += __shfl_xor(acc[i], 32);
    }
    dsum += __shfl_xor(dsum, 16);
    dsum += __shfl_xor(dsum, 32);

    if (q == 0) {
        float inv = 1.f / dsum;
        int c0 = p * 8;
        float v[8];
        #pragma unroll
        for (int i = 0; i < 8; ++i) v[i] = acc[i] * inv + bias[c0 + i];
        if (mode >= 1) {
            float4 p0 = *(const float4*)(&prev[(size_t)node * 128 + c0]);
            float4 p1 = *(const float4*)(&prev[(size_t)node * 128 + c0 + 4]);
            v[0] += p0.x; v[1] += p0.y; v[2] += p0.z; v[3] += p0.w;
            v[4] += p1.x; v[5] += p1.y; v[6] += p1.z; v[7] += p1.w;
        }
        #pragma unroll
        for (int i = 0; i < 8; ++i) v[i] = v[i] > 0.f ? v[i] : LEAK * v[i];
        if (mode == 2) {
            float partial = 0.f;
            #pragma unroll
            for (int i = 0; i < 8; ++i) partial += v[i] * lw[c0 + i];
            partial += __shfl_xor(partial, 1);
            partial += __shfl_xor(partial, 2);
            partial += __shfl_xor(partial, 4);
            partial += __shfl_xor(partial, 8);
            if (p == 0) logits[node] = partial + lb[0];
        } else {
            *(float4*)(&Out[(size_t)node * 128 + c0])     = make_float4(v[0], v[1], v[2], v[3]);
            *(float4*)(&Out[(size_t)node * 128 + c0 + 4]) = make_float4(v[4], v[5], v[6], v[7]);
        }
    }
}

// ================= launch =================

extern "C" void kernel_launch(void* const* d_in, const int* in_sizes, int n_in,
                              void* d_out, int out_size, void* d_ws, size_t ws_size,
                              hipStream_t stream) {
    const float* x    = (const float*)d_in[0];
    const int*   edge = (const int*)d_in[1];
    const float* W[3]  = {(const float*)d_in[2], (const float*)d_in[6], (const float*)d_in[10]};
    const float* as[3] = {(const float*)d_in[3], (const float*)d_in[7], (const float*)d_in[11]};
    const float* ad[3] = {(const float*)d_in[4], (const float*)d_in[8], (const float*)d_in[12]};
    const float* bs[3] = {(const float*)d_in[5], (const float*)d_in[9], (const float*)d_in[13]};
    const float* lw = (const float*)d_in[14];
    const float* lb = (const float*)d_in[15];

    const int N    = in_sizes[0] / 128;
    const int E    = in_sizes[1] / 2;
    const int ETOT = E + N;
    const int NBK  = (N + 127) >> 7;   // requires N <= 65536 (here N = 50000)

    char* base = (char*)d_ws;
    size_t o = 0;
    auto carve = [&](size_t bytes) {
        char* p = base + o;
        o = (o + bytes + 255) & ~(size_t)255;
        return p;
    };
    int*      off    = (int*)     carve((size_t)(N + 1) * 4);
    int*      gbkt   = (int*)     carve((size_t)(NBK + 1) * 4);
    int*      bko    = (int*)     carve((size_t)(NBK + 1) * 4);
    int*      gcur   = (int*)     carve((size_t)(NBK + 1) * 4);
    unsigned* binned = (unsigned*)carve((size_t)ETOT * 4);
    int*      csr    = (int*)     carve((size_t)ETOT * 4);
    float*    alsrc  = (float*)   carve((size_t)N * 2 * 4);
    float*    aldst  = (float*)   carve((size_t)N * 2 * 4);
    _Float16* h16    = (_Float16*)carve((size_t)N * 128 * 2);
    float*    bufA   = (float*)   carve((size_t)N * 128 * 4);
    float*    bufB   = (float*)   carve((size_t)N * 128 * 4);
    _Float16* w16    = (_Float16*)carve((size_t)3 * 16384 * 2);
    (void)ws_size; (void)n_in; (void)out_size;

    const int* esrc = edge;
    const int* edst = edge + E;

    int eb = (ETOT + 4095) / 4096;

    hipMemsetAsync(gbkt, 0, (size_t)(NBK + 1) * 4, stream);
    k_wconv<<<192, 256, 0, stream>>>(W[0], W[1], W[2], w16);

    // bucketed CSR build (4 dispatches)
    k_bincount<<<eb, 256, 0, stream>>>(edst, gbkt, E, ETOT, NBK);
    k_bktscan<<<1, 512, 0, stream>>>(gbkt, bko, gcur, NBK);
    k_binscatter<<<eb, 256, 0, stream>>>(esrc, edst, gcur, binned, E, ETOT, NBK);
    k_scatter2<<<NBK, 256, 0, stream>>>(binned, bko, off, csr, N, NBK);

    int gemm_blocks = (N + 63) / 64;
    int node_blocks = (N * 64 + 255) / 256;

    // layer 1
    k_gemm_mfma<<<gemm_blocks, 256, 0, stream>>>(x, w16, as[0], ad[0], h16, alsrc, aldst, N);
    k_aggregate<<<node_blocks, 256, 0, stream>>>(h16, alsrc, aldst, off, csr,
                                                 bs[0], nullptr, bufA, lw, lb, nullptr, N, 0);
    // layer 2
    k_gemm_mfma<<<gemm_blocks, 256, 0, stream>>>(bufA, w16 + 16384, as[1], ad[1], h16, alsrc, aldst, N);
    k_aggregate<<<node_blocks, 256, 0, stream>>>(h16, alsrc, aldst, off, csr,
                                                 bs[1], bufA, bufB, lw, lb, nullptr, N, 1);
    // layer 3 (+ fused final linear)
    k_gemm_mfma<<<gemm_blocks, 256, 0, stream>>>(bufB, w16 + 32768, as[2], ad[2], h16, alsrc, aldst, N);
    k_aggregate<<<node_blocks, 256, 0, stream>>>(h16, alsrc, aldst, off, csr,
                                                 bs[2], bufB, nullptr, lw, lb, (float*)d_out, N, 2);
}

// Round 8
// 290.202 us; speedup vs baseline: 1.6739x; 1.0412x over previous
//
#include <hip/hip_runtime.h>
#include <hip/hip_bf16.h>
#include <hip/hip_fp16.h>

#define LEAK 0.2f

typedef _Float16 half8  __attribute__((ext_vector_type(8)));
typedef _Float16 half4v __attribute__((ext_vector_type(4)));
typedef float    float4v __attribute__((ext_vector_type(4)));

// ================= bucketed CSR build =================
// bucket b = dst >> 7 (128 nodes/bucket). NBK <= 512. packed: src | (dloc<<17)

__global__ __launch_bounds__(256) void k_bincount(const int* __restrict__ edst,
                                                  int* __restrict__ gbkt,
                                                  int E, int ETOT, int NBK) {
    __shared__ int lh[512];
    int t = threadIdx.x;
    for (int b = t; b < NBK; b += 256) lh[b] = 0;
    __syncthreads();
    int base = blockIdx.x * 4096;
    #pragma unroll
    for (int u = 0; u < 16; ++u) {
        int e = base + u * 256 + t;
        if (e < ETOT) {
            int d = (e < E) ? edst[e] : (e - E);
            atomicAdd(&lh[d >> 7], 1);
        }
    }
    __syncthreads();
    for (int b = t; b < NBK; b += 256)
        if (lh[b]) atomicAdd(&gbkt[b], lh[b]);
}

__global__ __launch_bounds__(512) void k_bktscan(const int* __restrict__ gbkt,
                                                 int* __restrict__ bko,
                                                 int* __restrict__ gcur, int NBK) {
    int t = threadIdx.x;
    int v = (t < NBK) ? gbkt[t] : 0;
    int lane = t & 63, wid = t >> 6;
    int x = v;
    #pragma unroll
    for (int o = 1; o < 64; o <<= 1) {
        int y = __shfl_up(x, o);
        if (lane >= o) x += y;
    }
    __shared__ int ws[8];
    if (lane == 63) ws[wid] = x;
    __syncthreads();
    if (wid == 0) {
        int s = (lane < 8) ? ws[lane] : 0;
        #pragma unroll
        for (int o = 1; o < 8; o <<= 1) {
            int y = __shfl_up(s, o);
            if (lane >= o) s += y;
        }
        if (lane < 8) ws[lane] = s;
    }
    __syncthreads();
    int excl = x - v + (wid > 0 ? ws[wid - 1] : 0);
    if (t < NBK) { bko[t] = excl; gcur[t] = excl; }
    if (t == 511) bko[NBK] = excl;
}

__global__ __launch_bounds__(256) void k_binscatter(const int* __restrict__ esrc,
                                                    const int* __restrict__ edst,
                                                    int* __restrict__ gcur,
                                                    unsigned int* __restrict__ binned,
                                                    int E, int ETOT, int NBK) {
    __shared__ int lh[512];
    __shared__ int lbase[512];
    int t = threadIdx.x;
    for (int b = t; b < NBK; b += 256) lh[b] = 0;
    __syncthreads();
    int base = blockIdx.x * 4096;
    unsigned int word[16]; int bb[16], rk[16];
    #pragma unroll
    for (int u = 0; u < 16; ++u) {
        int e = base + u * 256 + t;
        bb[u] = -1;
        if (e < ETOT) {
            int s, d;
            if (e < E) { s = esrc[e]; d = edst[e]; } else { s = d = e - E; }
            int b = d >> 7;
            bb[u] = b;
            rk[u] = atomicAdd(&lh[b], 1);
            word[u] = (unsigned int)s | ((unsigned int)(d & 127) << 17);
        }
    }
    __syncthreads();
    for (int b = t; b < NBK; b += 256) {
        int c = lh[b];
        lbase[b] = c ? atomicAdd(&gcur[b], c) : 0;
    }
    __syncthreads();
    #pragma unroll
    for (int u = 0; u < 16; ++u)
        if (bb[u] >= 0) binned[lbase[bb[u]] + rk[u]] = word[u];
}

// fused: per-bucket degree count + LDS scan -> off[] + scatter into csr
__global__ __launch_bounds__(256) void k_scatter2(const unsigned int* __restrict__ binned,
                                                  const int* __restrict__ bko,
                                                  int* __restrict__ off,
                                                  int* __restrict__ csr, int N, int NBK) {
    __shared__ int deg[128];
    __shared__ int lcur[128];
    __shared__ int wt[2];
    int b = blockIdx.x, t = threadIdx.x;
    int n0 = b << 7;
    if (t < 128) deg[t] = 0;
    __syncthreads();
    int beg = bko[b], end = bko[b + 1];
    for (int i = beg + t; i < end; i += 256)
        atomicAdd(&deg[binned[i] >> 17], 1);
    __syncthreads();
    int v = 0, x = 0;
    if (t < 128) {
        v = deg[t];
        x = v;
        int lane = t & 63;
        #pragma unroll
        for (int o = 1; o < 64; o <<= 1) {
            int y = __shfl_up(x, o);
            if (lane >= o) x += y;
        }
        if (lane == 63) wt[t >> 6] = x;
    }
    __syncthreads();
    if (t < 128) {
        int excl = x - v + ((t >= 64) ? wt[0] : 0) + beg;
        lcur[t] = excl;
        int node = n0 + t;
        if (node < N) off[node] = excl;
    }
    if (b == NBK - 1 && t == 0) off[N] = end;
    __syncthreads();
    for (int i = beg + t; i < end; i += 256) {
        unsigned int u = binned[i];
        int pos = atomicAdd(&lcur[u >> 17], 1);
        csr[pos] = (int)(u & 0x1FFFF);
    }
}

// ================= W -> fp16 TRANSPOSED (w16t[n*128+k]) =================
// 12 blocks: 3 matrices x 4 (64x64) tiles; LDS transpose for coalesced R+W.

__global__ __launch_bounds__(256) void k_wconv(const float* __restrict__ W0,
                                               const float* __restrict__ W1,
                                               const float* __restrict__ W2,
                                               _Float16* __restrict__ w16t) {
    __shared__ _Float16 tile[64][68];   // stride 68 halves -> 2-way bank alias (free)
    int m = blockIdx.x >> 2;
    int ti = (blockIdx.x >> 1) & 1, tj = blockIdx.x & 1;
    const float* src = (m == 0) ? W0 : (m == 1 ? W1 : W2);
    _Float16* dst = w16t + m * 16384;
    int t = threadIdx.x;
    for (int idx = t; idx < 4096; idx += 256) {
        int r = idx >> 6, c = idx & 63;   // r = k-local, c = n-local (coalesced read)
        tile[r][c] = (_Float16)src[(ti * 64 + r) * 128 + tj * 64 + c];
    }
    __syncthreads();
    for (int idx = t; idx < 4096; idx += 256) {
        int c = idx >> 6, r = idx & 63;   // r fast -> consecutive k (coalesced write)
        dst[(tj * 64 + c) * 128 + ti * 64 + r] = tile[r][c];
    }
}

// ================= MFMA fp16 GEMM + fused attention logits =================
// h interleaved [N][128] fp16. 16x16x32_f16 lane maps (m89-verified):
//   A[m][k]: m=lane&15, k=(lane>>4)*8+j ; B[k][n]: n=lane&15, k=(lane>>4)*8+j
//   C/D[r][c]: c=lane&15, r=(lane>>4)*4+reg
// WhT is transposed: WhT[n*128+k] -> B-fragment preload is 8x 16-B vector loads.

__global__ __launch_bounds__(256) void k_gemm_mfma(const float* __restrict__ X,
                                                   const _Float16* __restrict__ WhT,
                                                   const float* __restrict__ a_src,
                                                   const float* __restrict__ a_dst,
                                                   _Float16* __restrict__ Hout,
                                                   float* __restrict__ alsrc,
                                                   float* __restrict__ aldst, int N) {
    __shared__ _Float16 As[64][136];   // +8 pad -> 2-way bank aliasing only (free)
    __shared__ float sS[64][2];
    __shared__ float sD[64][2];
    const int t = threadIdx.x;
    const int lane = t & 63, w = t >> 6;
    const int block_row = blockIdx.x * 64;

    if (t < 128) { sS[t >> 1][t & 1] = 0.f; sD[t >> 1][t & 1] = 0.f; }

    #pragma unroll
    for (int it = 0; it < 8; ++it) {
        int i = t + 256 * it;
        int row = i >> 5, c4 = i & 31;
        int gr = block_row + row;
        float4 xv = make_float4(0.f, 0.f, 0.f, 0.f);
        if (gr < N) xv = *(const float4*)(X + (size_t)gr * 128 + c4 * 4);
        half4v hv;
        hv[0] = (_Float16)xv.x; hv[1] = (_Float16)xv.y;
        hv[2] = (_Float16)xv.z; hv[3] = (_Float16)xv.w;
        *(half4v*)(&As[row][c4 * 4]) = hv;
    }

    const int l15 = lane & 15, kq = (lane >> 4) * 8;
    half8 bf[2][4];
    #pragma unroll
    for (int ntl = 0; ntl < 2; ++ntl) {
        int n0 = (w * 2 + ntl) * 16 + l15;
        #pragma unroll
        for (int kt = 0; kt < 4; ++kt)
            bf[ntl][kt] = *(const half8*)(WhT + (size_t)n0 * 128 + kt * 32 + kq);
    }
    __syncthreads();

    float4v acc[4][2];
    #pragma unroll
    for (int mt = 0; mt < 4; ++mt)
        #pragma unroll
        for (int ntl = 0; ntl < 2; ++ntl)
            acc[mt][ntl] = (float4v){0.f, 0.f, 0.f, 0.f};

    #pragma unroll
    for (int kt = 0; kt < 4; ++kt) {
        half8 a[4];
        #pragma unroll
        for (int mt = 0; mt < 4; ++mt)
            a[mt] = *(const half8*)(&As[mt * 16 + l15][kt * 32 + kq]);
        #pragma unroll
        for (int mt = 0; mt < 4; ++mt)
            #pragma unroll
            for (int ntl = 0; ntl < 2; ++ntl)
                acc[mt][ntl] = __builtin_amdgcn_mfma_f32_16x16x32_f16(
                    a[mt], bf[ntl][kt], acc[mt][ntl], 0, 0, 0);
    }

    #pragma unroll
    for (int mt = 0; mt < 4; ++mt) {
        int r0 = block_row + mt * 16 + (lane >> 4) * 4;
        #pragma unroll
        for (int ntl = 0; ntl < 2; ++ntl) {
            int col = (w * 2 + ntl) * 16 + l15;
            #pragma unroll
            for (int reg = 0; reg < 4; ++reg) {
                int r = r0 + reg;
                if (r < N) Hout[(size_t)r * 128 + col] = (_Float16)acc[mt][ntl][reg];
            }
        }
    }

    // fused attention logits: wave covers cols [w*32, w*32+32) -> head = w>>1
    {
        int c0 = w * 32 + l15, c1 = c0 + 16;
        float as0 = a_src[c0], as1 = a_src[c1];
        float ad0 = a_dst[c0], ad1 = a_dst[c1];
        int head = w >> 1;
        #pragma unroll
        for (int mt = 0; mt < 4; ++mt) {
            #pragma unroll
            for (int reg = 0; reg < 4; ++reg) {
                float ps = (float)acc[mt][0][reg] * as0 + (float)acc[mt][1][reg] * as1;
                float pd = (float)acc[mt][0][reg] * ad0 + (float)acc[mt][1][reg] * ad1;
                #pragma unroll
                for (int o = 1; o < 16; o <<= 1) {
                    ps += __shfl_xor(ps, o);
                    pd += __shfl_xor(pd, o);
                }
                if (l15 == 0) {
                    int row = mt * 16 + (lane >> 4) * 4 + reg;
                    atomicAdd(&sS[row][head], ps);
                    atomicAdd(&sD[row][head], pd);
                }
            }
        }
    }
    __syncthreads();
    if (t < 128) {
        int row = t >> 1, head = t & 1;
        int gr = block_row + row;
        if (gr < N) {
            alsrc[gr * 2 + head] = sS[row][head];
            aldst[gr * 2 + head] = sD[row][head];
        }
    }
}

// ================= softmax-aggregate: TWO nodes per wave64 =================
// half = lane>>5 picks the node; hl = lane&31; p = hl&15 owns channels [8p,8p+8);
// q = hl>>4 processes edges == q (mod 2). One vector load covers 4 edges (1 KB/wave).
// No segment-max: logits bounded, exp safe in fp32, softmax shift-invariant.
// mode: 0 = bias->Out ; 1 = bias+prev->Out ; 2 = bias+prev, fused lin dot -> logits

__global__ __launch_bounds__(256) void k_aggregate(
        const _Float16* __restrict__ H16,   // [N][128] fp16
        const float* __restrict__ alsrc,
        const float* __restrict__ aldst,
        const int* __restrict__ off, const int* __restrict__ csr,
        const float* __restrict__ bias,
        const float* __restrict__ prev,
        float* __restrict__ Out,
        const float* __restrict__ lw, const float* __restrict__ lb,
        float* __restrict__ logits, int N, int mode) {
    int wglobal = (int)((blockIdx.x * 256 + threadIdx.x) >> 6);
    int lane = threadIdx.x & 63;
    if (wglobal * 2 >= N) return;
    int half = lane >> 5;
    int hl = lane & 31;
    int node = wglobal * 2 + half;
    bool active = node < N;
    int nodeC = active ? node : (N - 1);
    int beg = off[nodeC];
    int end = active ? off[nodeC + 1] : beg;   // inactive half: empty range
    float ad0 = aldst[nodeC * 2], ad1 = aldst[nodeC * 2 + 1];

    int p = hl & 15;
    int q = hl >> 4;
    bool head0 = p < 8;
    const _Float16* hbase = H16 + p * 8;
    int hb = half << 5;

    float acc[8];
    #pragma unroll
    for (int k = 0; k < 8; ++k) acc[k] = 0.f;
    float dsum = 0.f;

    for (int base = beg; base < end; base += 32) {
        int i = base + hl;
        int s = 0; float w0 = 0.f, w1 = 0.f;
        if (i < end) {
            s = csr[i];
            float2 al = *(const float2*)(&alsrc[s * 2]);
            float e0 = al.x + ad0; e0 = e0 > 0.f ? e0 : LEAK * e0;
            float e1 = al.y + ad1; e1 = e1 > 0.f ? e1 : LEAK * e1;
            w0 = __expf(e0); w1 = __expf(e1);
        }
        int cnt = min(32, end - base);
        int iters = (cnt + 1) >> 1;
        int jj = 0;
        // 2x unrolled: two independent 1-KB (4-edge) gathers in flight
        for (; jj + 2 <= iters; jj += 2) {
            int sl0 = hb + (jj << 1) + q;
            int sl1 = sl0 + 2;
            int   sj0 = __shfl(s,  sl0);
            float w00 = __shfl(w0, sl0);
            float w10 = __shfl(w1, sl0);
            int   sj1 = __shfl(s,  sl1);
            float w01 = __shfl(w0, sl1);
            float w11 = __shfl(w1, sl1);
            float ws0 = head0 ? w00 : w10;
            float ws1 = head0 ? w01 : w11;
            uint4 raw0 = *(const uint4*)(hbase + (size_t)sj0 * 128);
            uint4 raw1 = *(const uint4*)(hbase + (size_t)sj1 * 128);
            const _Float16* h0 = (const _Float16*)&raw0;
            const _Float16* h1 = (const _Float16*)&raw1;
            #pragma unroll
            for (int k = 0; k < 8; ++k) acc[k] += ws0 * (float)h0[k];
            #pragma unroll
            for (int k = 0; k < 8; ++k) acc[k] += ws1 * (float)h1[k];
            dsum += ws0 + ws1;
        }
        if (jj < iters) {
            int sl = hb + (jj << 1) + q;
            int   sj = __shfl(s,  sl);
            float wa = __shfl(w0, sl);
            float wb = __shfl(w1, sl);
            float ws = head0 ? wa : wb;
            uint4 raw = *(const uint4*)(hbase + (size_t)sj * 128);
            const _Float16* h = (const _Float16*)&raw;
            #pragma unroll
            for (int k = 0; k < 8; ++k) acc[k] += ws * (float)h[k];
            dsum += ws;
        }
    }

    // merge the two q-groups within each half (NOT across halves!)
    #pragma unroll
    for (int k = 0; k < 8; ++k) acc[k] += __shfl_xor(acc[k], 16);
    dsum += __shfl_xor(dsum, 16);

    if (q == 0 && active) {
        float inv = 1.f / dsum;
        int c0 = p * 8;
        float v[8];
        #pragma unroll
        for (int k = 0; k < 8; ++k) v[k] = acc[k] * inv + bias[c0 + k];
        if (mode >= 1) {
            float4 p0 = *(const float4*)(&prev[(size_t)node * 128 + c0]);
            float4 p1 = *(const float4*)(&prev[(size_t)node * 128 + c0 + 4]);
            v[0] += p0.x; v[1] += p0.y; v[2] += p0.z; v[3] += p0.w;
            v[4] += p1.x; v[5] += p1.y; v[6] += p1.z; v[7] += p1.w;
        }
        #pragma unroll
        for (int k = 0; k < 8; ++k) v[k] = v[k] > 0.f ? v[k] : LEAK * v[k];
        if (mode == 2) {
            float partial = 0.f;
            #pragma unroll
            for (int k = 0; k < 8; ++k) partial += v[k] * lw[c0 + k];
            partial += __shfl_xor(partial, 1);
            partial += __shfl_xor(partial, 2);
            partial += __shfl_xor(partial, 4);
            partial += __shfl_xor(partial, 8);
            if (hl == 0) logits[node] = partial + lb[0];
        } else {
            *(float4*)(&Out[(size_t)node * 128 + c0])     = make_float4(v[0], v[1], v[2], v[3]);
            *(float4*)(&Out[(size_t)node * 128 + c0 + 4]) = make_float4(v[4], v[5], v[6], v[7]);
        }
    }
}

// ================= launch =================

extern "C" void kernel_launch(void* const* d_in, const int* in_sizes, int n_in,
                              void* d_out, int out_size, void* d_ws, size_t ws_size,
                              hipStream_t stream) {
    const float* x    = (const float*)d_in[0];
    const int*   edge = (const int*)d_in[1];
    const float* W[3]  = {(const float*)d_in[2], (const float*)d_in[6], (const float*)d_in[10]};
    const float* as[3] = {(const float*)d_in[3], (const float*)d_in[7], (const float*)d_in[11]};
    const float* ad[3] = {(const float*)d_in[4], (const float*)d_in[8], (const float*)d_in[12]};
    const float* bs[3] = {(const float*)d_in[5], (const float*)d_in[9], (const float*)d_in[13]};
    const float* lw = (const float*)d_in[14];
    const float* lb = (const float*)d_in[15];

    const int N    = in_sizes[0] / 128;
    const int E    = in_sizes[1] / 2;
    const int ETOT = E + N;
    const int NBK  = (N + 127) >> 7;   // requires N <= 65536 (here N = 50000)

    char* base = (char*)d_ws;
    size_t o = 0;
    auto carve = [&](size_t bytes) {
        char* p = base + o;
        o = (o + bytes + 255) & ~(size_t)255;
        return p;
    };
    int*      off    = (int*)     carve((size_t)(N + 1) * 4);
    int*      gbkt   = (int*)     carve((size_t)(NBK + 1) * 4);
    int*      bko    = (int*)     carve((size_t)(NBK + 1) * 4);
    int*      gcur   = (int*)     carve((size_t)(NBK + 1) * 4);
    unsigned* binned = (unsigned*)carve((size_t)ETOT * 4);
    int*      csr    = (int*)     carve((size_t)ETOT * 4);
    float*    alsrc  = (float*)   carve((size_t)N * 2 * 4);
    float*    aldst  = (float*)   carve((size_t)N * 2 * 4);
    _Float16* h16    = (_Float16*)carve((size_t)N * 128 * 2);
    float*    bufA   = (float*)   carve((size_t)N * 128 * 4);
    float*    bufB   = (float*)   carve((size_t)N * 128 * 4);
    _Float16* w16t   = (_Float16*)carve((size_t)3 * 16384 * 2);
    (void)ws_size; (void)n_in; (void)out_size;

    const int* esrc = edge;
    const int* edst = edge + E;

    int eb = (ETOT + 4095) / 4096;

    hipMemsetAsync(gbkt, 0, (size_t)(NBK + 1) * 4, stream);
    k_wconv<<<12, 256, 0, stream>>>(W[0], W[1], W[2], w16t);

    // bucketed CSR build (4 dispatches)
    k_bincount<<<eb, 256, 0, stream>>>(edst, gbkt, E, ETOT, NBK);
    k_bktscan<<<1, 512, 0, stream>>>(gbkt, bko, gcur, NBK);
    k_binscatter<<<eb, 256, 0, stream>>>(esrc, edst, gcur, binned, E, ETOT, NBK);
    k_scatter2<<<NBK, 256, 0, stream>>>(binned, bko, off, csr, N, NBK);

    int gemm_blocks = (N + 63) / 64;
    int agg_blocks  = (N + 7) / 8;     // 2 nodes per wave, 4 waves per block

    // layer 1
    k_gemm_mfma<<<gemm_blocks, 256, 0, stream>>>(x, w16t, as[0], ad[0], h16, alsrc, aldst, N);
    k_aggregate<<<agg_blocks, 256, 0, stream>>>(h16, alsrc, aldst, off, csr,
                                                bs[0], nullptr, bufA, lw, lb, nullptr, N, 0);
    // layer 2
    k_gemm_mfma<<<gemm_blocks, 256, 0, stream>>>(bufA, w16t + 16384, as[1], ad[1], h16, alsrc, aldst, N);
    k_aggregate<<<agg_blocks, 256, 0, stream>>>(h16, alsrc, aldst, off, csr,
                                                bs[1], bufA, bufB, lw, lb, nullptr, N, 1);
    // layer 3 (+ fused final linear)
    k_gemm_mfma<<<gemm_blocks, 256, 0, stream>>>(bufB, w16t + 32768, as[2], ad[2], h16, alsrc, aldst, N);
    k_aggregate<<<agg_blocks, 256, 0, stream>>>(h16, alsrc, aldst, off, csr,
                                                bs[2], bufB, nullptr, lw, lb, (float*)d_out, N, 2);
}